// Round 6
// baseline (9303.824 us; speedup 1.0000x reference)
//
#include <hip/hip_runtime.h>
#include <cstdint>

// ---------------- fast device math (raw v_exp_f32 / v_rcp_f32) ----------------
__device__ __forceinline__ float fexp2(float x) { return __builtin_amdgcn_exp2f(x); }
__device__ __forceinline__ float frcp(float x)  { return __builtin_amdgcn_rcpf(x); }

__device__ __forceinline__ float fast_tanh(float x) {
    x = fminf(15.0f, fmaxf(-15.0f, x));
    float E = fexp2(x * 2.8853900817779268f);   // exp(2x) = 2^(2x*log2e)
    float d = E + 1.0f;
    float r = frcp(d);
    r = r * (2.0f - d * r);                      // Newton -> ~fp32 precise
    return (E - 1.0f) * r;
}

// ---------------- tiled fp32 GEMM: C[M][N] = act(A[M][K] @ W[K][N] + bias) ----
#define BM 64
#define BN 64
#define BK 16

template<bool TANH>
__global__ __launch_bounds__(256) void gemm_bias(
    const float* __restrict__ A, const float* __restrict__ W,
    const float* __restrict__ bias, float* __restrict__ C,
    int M, int N, int K)
{
    __shared__ float As[BK][BM + 4];
    __shared__ float Bs[BK][BN + 4];

    const int tid = threadIdx.x;
    const int tx = tid & 15;
    const int ty = tid >> 4;
    const int m0 = blockIdx.y * BM;
    const int n0 = blockIdx.x * BN;

    float acc[4][4] = {};

    for (int k0 = 0; k0 < K; k0 += BK) {
        #pragma unroll
        for (int ld = 0; ld < 4; ++ld) {
            int e  = tid + ld * 256;
            int kk = e & 15, mm = e >> 4;
            int kg = k0 + kk;
            As[kk][mm] = (kg < K) ? A[(size_t)(m0 + mm) * K + kg] : 0.0f;
        }
        #pragma unroll
        for (int ld = 0; ld < 4; ++ld) {
            int e  = tid + ld * 256;
            int nn = e & 63, kk = e >> 6;
            int kg = k0 + kk, ng = n0 + nn;
            Bs[kk][nn] = (kg < K && ng < N) ? W[(size_t)kg * N + ng] : 0.0f;
        }
        __syncthreads();

        #pragma unroll
        for (int kk = 0; kk < BK; ++kk) {
            float4 a  = *(const float4*)&As[kk][ty * 4];
            float4 bq = *(const float4*)&Bs[kk][tx * 4];
            float av[4] = {a.x, a.y, a.z, a.w};
            float bv[4] = {bq.x, bq.y, bq.z, bq.w};
            #pragma unroll
            for (int i2 = 0; i2 < 4; ++i2)
                #pragma unroll
                for (int j2 = 0; j2 < 4; ++j2)
                    acc[i2][j2] += av[i2] * bv[j2];
        }
        __syncthreads();
    }

    const int cbase = n0 + tx * 4;
    if (cbase >= N) return;

    float bb[4];
    if (cbase + 3 < N) {
        float4 b4 = *(const float4*)&bias[cbase];
        bb[0] = b4.x; bb[1] = b4.y; bb[2] = b4.z; bb[3] = b4.w;
    } else {
        #pragma unroll
        for (int e = 0; e < 4; ++e) bb[e] = (cbase + e < N) ? bias[cbase + e] : 0.0f;
    }

    #pragma unroll
    for (int i2 = 0; i2 < 4; ++i2) {
        int row = m0 + ty * 4 + i2;
        float o[4];
        #pragma unroll
        for (int j2 = 0; j2 < 4; ++j2) {
            float v = acc[i2][j2] + bb[j2];
            o[j2] = TANH ? fast_tanh(v) : v;
        }
        if (cbase + 3 < N) {
            float4 o4 = {o[0], o[1], o[2], o[3]};
            *(float4*)&C[(size_t)row * N + cbase] = o4;
        } else {
            #pragma unroll
            for (int j2 = 0; j2 < 4; ++j2)
                if (cbase + j2 < N) C[(size_t)row * N + cbase + j2] = o[j2];
        }
    }
}

// ---------------- decoder layer 1 (K=4) --------------------------------------
__global__ __launch_bounds__(256) void dec_l1(
    const float* __restrict__ Mo, const float* __restrict__ Wd,
    const float* __restrict__ bd, float* __restrict__ O)
{
    int idx = blockIdx.x * 256 + threadIdx.x;
    int r  = idx / 125;
    int c4 = (idx % 125) * 4;
    float4 m = *(const float4*)&Mo[(size_t)r * 4];
    float4 w0 = *(const float4*)&Wd[0 * 500 + c4];
    float4 w1 = *(const float4*)&Wd[1 * 500 + c4];
    float4 w2 = *(const float4*)&Wd[2 * 500 + c4];
    float4 w3 = *(const float4*)&Wd[3 * 500 + c4];
    float4 b  = *(const float4*)&bd[c4];
    float o0 = b.x + m.x * w0.x + m.y * w1.x + m.z * w2.x + m.w * w3.x;
    float o1 = b.y + m.x * w0.y + m.y * w1.y + m.z * w2.y + m.w * w3.y;
    float o2 = b.z + m.x * w0.z + m.y * w1.z + m.z * w2.z + m.w * w3.z;
    float o3 = b.w + m.x * w0.w + m.y * w1.w + m.z * w2.w + m.w * w3.w;
    float4 o = {fast_tanh(o0), fast_tanh(o1), fast_tanh(o2), fast_tanh(o3)};
    *(float4*)&O[(size_t)r * 500 + c4] = o;
}

// ---------------- LTC scan: 1 block/batch, 16 waves (1024 thr), lane = j -----
// Wave w (0..15) owns presynaptic i in [4w, 4w+4). Every wave keeps the full
// v vector (lane j holds v_j, identical in all waves); v_i via v_readlane.
// Trans-issue optimization (trans ~16cyc/wave64 is 65% of issue on R5):
//   batched reciprocal: rcp(F0*F1*F2*F3) + 9 muls -> all four 1/F_i.
//   4 exp + 1 rcp per wave-unfold instead of 8 exp + 8 rcp (R5 per-wave).
// Reduce: ds_add_f32 atomics into triple-buffered AN/AD[3][64] (2 LDS ops per
// wave instead of 16 reads + 16 adds). Buffer b_{k-1} is zeroed by waves 0/1
// right AFTER barrier k (all reads of it completed before barrier k) and only
// receives adds again after barrier k+1 -> race-free with 1 barrier/unfold.
// Atomic f32 ordering noise ~1e-5, well inside the 1e-2 threshold.
#define SEQ_T 512

__global__ __launch_bounds__(1024, 1) void ltc_scan(
    const float* __restrict__ h,       // [32][512][20]
    const float* __restrict__ gleak, const float* __restrict__ vleak,
    const float* __restrict__ cm,
    const float* __restrict__ w,  const float* __restrict__ mu,
    const float* __restrict__ sg, const float* __restrict__ erev,
    const float* __restrict__ sw,  const float* __restrict__ smu,
    const float* __restrict__ ssg, const float* __restrict__ serev,
    const float* __restrict__ in_w, const float* __restrict__ in_b,
    const float* __restrict__ out_w, const float* __restrict__ out_b,
    float* __restrict__ motor)         // [32][512][4]
{
    const int b   = blockIdx.x;
    const int tid = threadIdx.x;
    const int w16 = tid >> 6;          // wave 0..15
    const int j   = tid & 63;          // postsynaptic unit

    const float LOG2E = 1.4426950408889634f;

    __shared__ float AN[3][64];        // triple-buffered atomic partials
    __shared__ float AD[3][64];

    // zero all buffers once
    if (tid < 192) { ((float*)AN)[tid] = 0.0f; ((float*)AD)[tid] = 0.0f; }

    // unfold params for (i = 4*w16 + r, j):  x = B1 - vi*A1 (= -y*log2e)
    float A1[4], B1[4], Wp[4], WE[4];
    #pragma unroll
    for (int r = 0; r < 4; ++r) {
        int i = 4 * w16 + r;
        float s = sg[i * 64 + j];
        A1[r] = s * LOG2E;
        B1[r] = mu[i * 64 + j] * s * LOG2E;
        Wp[r] = w[i * 64 + j];
        WE[r] = Wp[r] * erev[i * 64 + j];
    }
    // sensory: wave w takes i=w; waves 0-3 also take i=16+w  (total 20)
    const int nsen = (w16 < 4) ? 2 : 1;
    float sA[2], sB[2], sWp[2], sWE[2], uw[2], ub[2];
    int   sI[2];
    #pragma unroll
    for (int r = 0; r < 2; ++r) {
        int i = (r == 0) ? w16 : (16 + w16);
        bool live = (i < 20);
        sI[r] = live ? i : 0;
        float s = ssg[sI[r] * 64 + j];
        sA[r]  = s * LOG2E;
        sB[r]  = smu[sI[r] * 64 + j] * s * LOG2E;
        sWp[r] = live ? sw[sI[r] * 64 + j] : 0.0f;
        sWE[r] = live ? sWp[r] * serev[sI[r] * 64 + j] : 0.0f;
        uw[r]  = in_w[sI[r]];
        ub[r]  = in_b[sI[r]];
    }

    const float cmt  = cm[j] * 6.0f;
    const float gl   = gleak[j];
    const float glvl = gl * vleak[j];
    const float ow   = out_w[j & 3], ob = out_b[j & 3];

    float vj = 0.0f;
    const float* hb = h + (size_t)b * SEQ_T * 20;
    float* mb = motor + (size_t)b * SEQ_T * 4;

    float u_cur[2], u_nxt[2];
    #pragma unroll
    for (int r = 0; r < 2; ++r) u_cur[r] = hb[sI[r]];

    __syncthreads();   // buffers zeroed

    int bk = 0;        // current accumulation buffer (unfold_index % 3)
    for (int t = 0; t < SEQ_T; ++t) {
        int tn = (t + 1 < SEQ_T) ? (t + 1) : t;
        #pragma unroll
        for (int r = 0; r < 2; ++r) u_nxt[r] = hb[tn * 20 + sI[r]];

        // sensory partial for this wave (amortized over 6 unfolds)
        float ns = 0.0f, ds = 0.0f;
        for (int r = 0; r < nsen; ++r) {
            float ui = fmaf(u_cur[r], uw[r], ub[r]);
            float x  = sB[r] - ui * sA[r];
            float E  = fexp2(x);
            float s  = frcp(1.0f + E);
            ns = fmaf(sWE[r], s, ns);
            ds = fmaf(sWp[r], s, ds);
        }

        #pragma unroll 1
        for (int uf = 0; uf < 6; ++uf) {
            // 4 synapses, batched reciprocal (4 exp + 1 rcp)
            float F[4];
            #pragma unroll
            for (int r = 0; r < 4; ++r) {
                float vi = __uint_as_float(
                    __builtin_amdgcn_readlane(__float_as_uint(vj), 4 * w16 + r));
                float x = fmaf(-vi, A1[r], B1[r]);
                x = fminf(fmaxf(x, -28.0f), 28.0f);   // product of 4 <= 2^112
                F[r] = 1.0f + fexp2(x);
            }
            float g01 = F[0] * F[1], g23 = F[2] * F[3];
            float rp  = frcp(g01 * g23);
            float r01 = g23 * rp;                      // 1/(F0*F1)
            float r23 = g01 * rp;                      // 1/(F2*F3)
            float s0 = F[1] * r01, s1 = F[0] * r01;
            float s2 = F[3] * r23, s3 = F[2] * r23;
            float an = ns, ad = ds;
            an = fmaf(WE[0], s0, an); ad = fmaf(Wp[0], s0, ad);
            an = fmaf(WE[1], s1, an); ad = fmaf(Wp[1], s1, ad);
            an = fmaf(WE[2], s2, an); ad = fmaf(Wp[2], s2, ad);
            an = fmaf(WE[3], s3, an); ad = fmaf(Wp[3], s3, ad);

            atomicAdd(&AN[bk][j], an);
            atomicAdd(&AD[bk][j], ad);
            __syncthreads();

            // zero the buffer from 2 unfolds ago (reused 1 unfold from now)
            int zb = bk + 2; if (zb >= 3) zb -= 3;
            if (w16 == 0)      AN[zb][j] = 0.0f;
            else if (w16 == 1) AD[zb][j] = 0.0f;

            float num = fmaf(cmt, vj, glvl) + AN[bk][j];
            float den = cmt + gl + 1e-8f + AD[bk][j];
            vj = num * frcp(den);
            bk = bk + 1; if (bk >= 3) bk = 0;
        }

        if (w16 == 0 && j < 4) mb[t * 4 + j] = fmaf(vj, ow, ob);

        #pragma unroll
        for (int r = 0; r < 2; ++r) u_cur[r] = u_nxt[r];
    }
}

// ---------------- launch --------------------------------------------------
extern "C" void kernel_launch(void* const* d_in, const int* in_sizes, int n_in,
                              void* d_out, int out_size, void* d_ws, size_t ws_size,
                              hipStream_t stream) {
    const float* x      = (const float*)d_in[0];
    const float* enc_w0 = (const float*)d_in[1];
    const float* enc_b0 = (const float*)d_in[2];
    const float* enc_w1 = (const float*)d_in[3];
    const float* enc_b1 = (const float*)d_in[4];
    const float* enc_w2 = (const float*)d_in[5];
    const float* enc_b2 = (const float*)d_in[6];
    const float* dec_w0 = (const float*)d_in[7];
    const float* dec_b0 = (const float*)d_in[8];
    const float* dec_w1 = (const float*)d_in[9];
    const float* dec_b1 = (const float*)d_in[10];
    const float* dec_w2 = (const float*)d_in[11];
    const float* dec_b2 = (const float*)d_in[12];
    const float* gleak  = (const float*)d_in[13];
    const float* vleak  = (const float*)d_in[14];
    const float* cm     = (const float*)d_in[15];
    const float* w      = (const float*)d_in[16];
    const float* mu     = (const float*)d_in[17];
    const float* sigma  = (const float*)d_in[18];
    const float* erev   = (const float*)d_in[19];
    const float* sw     = (const float*)d_in[20];
    const float* smu    = (const float*)d_in[21];
    const float* ssigma = (const float*)d_in[22];
    const float* serev  = (const float*)d_in[23];
    const float* in_w   = (const float*)d_in[24];
    const float* in_b   = (const float*)d_in[25];
    const float* out_w  = (const float*)d_in[26];
    const float* out_b  = (const float*)d_in[27];

    float* ws   = (float*)d_ws;
    float* buf1 = ws;                       // 16384*500
    float* buf2 = ws + 8192000;             // 16384*500
    float* hbuf = ws + 16384000;            // 16384*20
    float* mbuf = ws + 16384000 + 327680;   // 16384*4

    dim3 blk(256);
    // encoder
    gemm_bias<true ><<<dim3(8, 256), blk, 0, stream>>>(x,    enc_w0, enc_b0, buf1, 16384, 500, 39);
    gemm_bias<true ><<<dim3(8, 256), blk, 0, stream>>>(buf1, enc_w1, enc_b1, buf2, 16384, 500, 500);
    gemm_bias<false><<<dim3(1, 256), blk, 0, stream>>>(buf2, enc_w2, enc_b2, hbuf, 16384, 20, 500);
    // LTC scan
    ltc_scan<<<dim3(32), dim3(1024), 0, stream>>>(hbuf, gleak, vleak, cm, w, mu, sigma, erev,
                                                  sw, smu, ssigma, serev, in_w, in_b, out_w, out_b, mbuf);
    // decoder
    dec_l1<<<dim3(8000), blk, 0, stream>>>(mbuf, dec_w0, dec_b0, buf1);
    gemm_bias<true ><<<dim3(8, 256), blk, 0, stream>>>(buf1, dec_w1, dec_b1, buf2, 16384, 500, 500);
    gemm_bias<false><<<dim3(1, 256), blk, 0, stream>>>(buf2, dec_w2, dec_b2, (float*)d_out, 16384, 30, 500);
}

// Round 7
// 2404.834 us; speedup vs baseline: 3.8688x; 3.8688x over previous
//
#include <hip/hip_runtime.h>
#include <cstdint>

// ---------------- fast device math (raw v_exp_f32 / v_rcp_f32) ----------------
__device__ __forceinline__ float fexp2(float x) { return __builtin_amdgcn_exp2f(x); }
__device__ __forceinline__ float frcp(float x)  { return __builtin_amdgcn_rcpf(x); }

__device__ __forceinline__ float fast_tanh(float x) {
    x = fminf(15.0f, fmaxf(-15.0f, x));
    float E = fexp2(x * 2.8853900817779268f);   // exp(2x) = 2^(2x*log2e)
    float d = E + 1.0f;
    float r = frcp(d);
    r = r * (2.0f - d * r);                      // Newton -> ~fp32 precise
    return (E - 1.0f) * r;
}

// ---------------- tiled fp32 GEMM: C[M][N] = act(A[M][K] @ W[K][N] + bias) ----
#define BM 64
#define BN 64
#define BK 16

template<bool TANH>
__global__ __launch_bounds__(256) void gemm_bias(
    const float* __restrict__ A, const float* __restrict__ W,
    const float* __restrict__ bias, float* __restrict__ C,
    int M, int N, int K)
{
    __shared__ float As[BK][BM + 4];
    __shared__ float Bs[BK][BN + 4];

    const int tid = threadIdx.x;
    const int tx = tid & 15;
    const int ty = tid >> 4;
    const int m0 = blockIdx.y * BM;
    const int n0 = blockIdx.x * BN;

    float acc[4][4] = {};

    for (int k0 = 0; k0 < K; k0 += BK) {
        #pragma unroll
        for (int ld = 0; ld < 4; ++ld) {
            int e  = tid + ld * 256;
            int kk = e & 15, mm = e >> 4;
            int kg = k0 + kk;
            As[kk][mm] = (kg < K) ? A[(size_t)(m0 + mm) * K + kg] : 0.0f;
        }
        #pragma unroll
        for (int ld = 0; ld < 4; ++ld) {
            int e  = tid + ld * 256;
            int nn = e & 63, kk = e >> 6;
            int kg = k0 + kk, ng = n0 + nn;
            Bs[kk][nn] = (kg < K && ng < N) ? W[(size_t)kg * N + ng] : 0.0f;
        }
        __syncthreads();

        #pragma unroll
        for (int kk = 0; kk < BK; ++kk) {
            float4 a  = *(const float4*)&As[kk][ty * 4];
            float4 bq = *(const float4*)&Bs[kk][tx * 4];
            float av[4] = {a.x, a.y, a.z, a.w};
            float bv[4] = {bq.x, bq.y, bq.z, bq.w};
            #pragma unroll
            for (int i2 = 0; i2 < 4; ++i2)
                #pragma unroll
                for (int j2 = 0; j2 < 4; ++j2)
                    acc[i2][j2] += av[i2] * bv[j2];
        }
        __syncthreads();
    }

    const int cbase = n0 + tx * 4;
    if (cbase >= N) return;

    float bb[4];
    if (cbase + 3 < N) {
        float4 b4 = *(const float4*)&bias[cbase];
        bb[0] = b4.x; bb[1] = b4.y; bb[2] = b4.z; bb[3] = b4.w;
    } else {
        #pragma unroll
        for (int e = 0; e < 4; ++e) bb[e] = (cbase + e < N) ? bias[cbase + e] : 0.0f;
    }

    #pragma unroll
    for (int i2 = 0; i2 < 4; ++i2) {
        int row = m0 + ty * 4 + i2;
        float o[4];
        #pragma unroll
        for (int j2 = 0; j2 < 4; ++j2) {
            float v = acc[i2][j2] + bb[j2];
            o[j2] = TANH ? fast_tanh(v) : v;
        }
        if (cbase + 3 < N) {
            float4 o4 = {o[0], o[1], o[2], o[3]};
            *(float4*)&C[(size_t)row * N + cbase] = o4;
        } else {
            #pragma unroll
            for (int j2 = 0; j2 < 4; ++j2)
                if (cbase + j2 < N) C[(size_t)row * N + cbase + j2] = o[j2];
        }
    }
}

// ---------------- decoder layer 1 (K=4) --------------------------------------
__global__ __launch_bounds__(256) void dec_l1(
    const float* __restrict__ Mo, const float* __restrict__ Wd,
    const float* __restrict__ bd, float* __restrict__ O)
{
    int idx = blockIdx.x * 256 + threadIdx.x;
    int r  = idx / 125;
    int c4 = (idx % 125) * 4;
    float4 m = *(const float4*)&Mo[(size_t)r * 4];
    float4 w0 = *(const float4*)&Wd[0 * 500 + c4];
    float4 w1 = *(const float4*)&Wd[1 * 500 + c4];
    float4 w2 = *(const float4*)&Wd[2 * 500 + c4];
    float4 w3 = *(const float4*)&Wd[3 * 500 + c4];
    float4 b  = *(const float4*)&bd[c4];
    float o0 = b.x + m.x * w0.x + m.y * w1.x + m.z * w2.x + m.w * w3.x;
    float o1 = b.y + m.x * w0.y + m.y * w1.y + m.z * w2.y + m.w * w3.y;
    float o2 = b.z + m.x * w0.z + m.y * w1.z + m.z * w2.z + m.w * w3.z;
    float o3 = b.w + m.x * w0.w + m.y * w1.w + m.z * w2.w + m.w * w3.w;
    float4 o = {fast_tanh(o0), fast_tanh(o1), fast_tanh(o2), fast_tanh(o3)};
    *(float4*)&O[(size_t)r * 500 + c4] = o;
}

// ---------------- LTC scan: 1 block/batch, 8 waves (512 thr), lane = unit j --
// R5 structure (best: 1648us, 0 conflicts) + batched reciprocal.
// Wave w owns presynaptic i in [8w, 8w+8); every wave keeps the full v vector
// (lane j holds v_j); v_i via v_readlane. Per wave-unfold: 8 exp + 2 rcp
// (was 8 exp + 8 rcp): rcp(F0*F1*F2*F3) + 9 muls reconstructs all four 1/Fi.
// No clamps needed: |v|<=1 (convex comb. of v,vleak,erev), sigma<=8 ->
// |x|<=8*log2e*1.8~21, group product <= 2^84 << 2^128. Reduce: conflict-free
// f32 partials AN/AD[2][8][64], ONE barrier per unfold, double-buffered.
// LDS atomics (R6) are banned: 16-wave same-address atomicAdd serialized the
// whole kernel (VALUBusy 1.8%, 5x regression).
#define SEQ_T 512

__global__ __launch_bounds__(512, 2) void ltc_scan(
    const float* __restrict__ h,       // [32][512][20]
    const float* __restrict__ gleak, const float* __restrict__ vleak,
    const float* __restrict__ cm,
    const float* __restrict__ w,  const float* __restrict__ mu,
    const float* __restrict__ sg, const float* __restrict__ erev,
    const float* __restrict__ sw,  const float* __restrict__ smu,
    const float* __restrict__ ssg, const float* __restrict__ serev,
    const float* __restrict__ in_w, const float* __restrict__ in_b,
    const float* __restrict__ out_w, const float* __restrict__ out_b,
    float* __restrict__ motor)         // [32][512][4]
{
    const int b   = blockIdx.x;
    const int tid = threadIdx.x;
    const int w8  = tid >> 6;          // wave 0..7
    const int j   = tid & 63;          // postsynaptic unit

    const float LOG2E = 1.4426950408889634f;

    __shared__ float AN[2][8][64];     // 2 KB  conflict-free partials
    __shared__ float AD[2][8][64];     // 2 KB

    // unfold params for (i = 8*w8 + r, j):  x = B1 - vi*A1  (= -y*log2e)
    float A1[8], B1[8], Wp[8], WE[8];
    #pragma unroll
    for (int r = 0; r < 8; ++r) {
        int i = 8 * w8 + r;
        float s = sg[i * 64 + j];
        A1[r] = s * LOG2E;
        B1[r] = mu[i * 64 + j] * s * LOG2E;
        Wp[r] = w[i * 64 + j];
        WE[r] = Wp[r] * erev[i * 64 + j];
    }
    // sensory params: i = w8, w8+8, and (w8<4 ? w8+16 : masked)
    float sA[3], sB[3], sWp[3], sWE[3], uw[3], ub[3];
    int   sI[3];
    #pragma unroll
    for (int r = 0; r < 3; ++r) {
        int i = w8 + 8 * r;
        bool live = (i < 20);
        sI[r] = live ? i : 0;
        float s = ssg[sI[r] * 64 + j];
        sA[r]  = s * LOG2E;
        sB[r]  = smu[sI[r] * 64 + j] * s * LOG2E;
        sWp[r] = live ? sw[sI[r] * 64 + j] : 0.0f;
        sWE[r] = live ? sWp[r] * serev[sI[r] * 64 + j] : 0.0f;
        uw[r]  = in_w[sI[r]];
        ub[r]  = in_b[sI[r]];
    }

    const float cmt  = cm[j] * 6.0f;
    const float gl   = gleak[j];
    const float glvl = gl * vleak[j];
    const float gle  = cmt + gl + 1e-8f;
    const float ow   = out_w[j & 3], ob = out_b[j & 3];

    float vj = 0.0f;
    const float* hb = h + (size_t)b * SEQ_T * 20;
    float* mb = motor + (size_t)b * SEQ_T * 4;

    float u_cur[3], u_nxt[3];
    #pragma unroll
    for (int r = 0; r < 3; ++r) u_cur[r] = hb[sI[r]];

    int buf = 0;
    for (int t = 0; t < SEQ_T; ++t) {
        int tn = (t + 1 < SEQ_T) ? (t + 1) : t;
        #pragma unroll
        for (int r = 0; r < 3; ++r) u_nxt[r] = hb[tn * 20 + sI[r]];

        // sensory partial for this wave (amortized over 6 unfolds; |x| can be
        // large here so keep per-synapse rcp)
        float ns = 0.0f, ds = 0.0f;
        #pragma unroll
        for (int r = 0; r < 3; ++r) {
            float ui = fmaf(u_cur[r], uw[r], ub[r]);
            float x  = sB[r] - ui * sA[r];
            float E  = fexp2(x);
            float s  = frcp(1.0f + E);
            ns = fmaf(sWE[r], s, ns);
            ds = fmaf(sWp[r], s, ds);
        }

        #pragma unroll 1
        for (int uf = 0; uf < 6; ++uf) {
            // 8 synapses: 8 exp + 2 batched rcp
            float F[8];
            #pragma unroll
            for (int r = 0; r < 8; ++r) {
                float vi = __uint_as_float(
                    __builtin_amdgcn_readlane(__float_as_uint(vj), 8 * w8 + r));
                float x = fmaf(-vi, A1[r], B1[r]);
                F[r] = 1.0f + fexp2(x);
            }
            float g01 = F[0] * F[1], g23 = F[2] * F[3];
            float g45 = F[4] * F[5], g67 = F[6] * F[7];
            float rp0 = frcp(g01 * g23);
            float rp1 = frcp(g45 * g67);
            float r01 = g23 * rp0, r23 = g01 * rp0;
            float r45 = g67 * rp1, r67 = g45 * rp1;
            float s0 = F[1] * r01, s1 = F[0] * r01;
            float s2 = F[3] * r23, s3 = F[2] * r23;
            float s4 = F[5] * r45, s5 = F[4] * r45;
            float s6 = F[7] * r67, s7 = F[6] * r67;

            float an = ns, ad = ds;
            an = fmaf(WE[0], s0, an); ad = fmaf(Wp[0], s0, ad);
            an = fmaf(WE[1], s1, an); ad = fmaf(Wp[1], s1, ad);
            an = fmaf(WE[2], s2, an); ad = fmaf(Wp[2], s2, ad);
            an = fmaf(WE[3], s3, an); ad = fmaf(Wp[3], s3, ad);
            an = fmaf(WE[4], s4, an); ad = fmaf(Wp[4], s4, ad);
            an = fmaf(WE[5], s5, an); ad = fmaf(Wp[5], s5, ad);
            an = fmaf(WE[6], s6, an); ad = fmaf(Wp[6], s6, ad);
            an = fmaf(WE[7], s7, an); ad = fmaf(Wp[7], s7, ad);

            AN[buf][w8][j] = an;
            AD[buf][w8][j] = ad;
            __syncthreads();
            float num = fmaf(cmt, vj, glvl);
            float den = gle;
            #pragma unroll
            for (int q = 0; q < 8; ++q) { num += AN[buf][q][j]; den += AD[buf][q][j]; }
            vj = num * frcp(den);
            buf ^= 1;
        }

        if (w8 == 0 && j < 4) mb[t * 4 + j] = fmaf(vj, ow, ob);

        #pragma unroll
        for (int r = 0; r < 3; ++r) u_cur[r] = u_nxt[r];
    }
}

// ---------------- launch --------------------------------------------------
extern "C" void kernel_launch(void* const* d_in, const int* in_sizes, int n_in,
                              void* d_out, int out_size, void* d_ws, size_t ws_size,
                              hipStream_t stream) {
    const float* x      = (const float*)d_in[0];
    const float* enc_w0 = (const float*)d_in[1];
    const float* enc_b0 = (const float*)d_in[2];
    const float* enc_w1 = (const float*)d_in[3];
    const float* enc_b1 = (const float*)d_in[4];
    const float* enc_w2 = (const float*)d_in[5];
    const float* enc_b2 = (const float*)d_in[6];
    const float* dec_w0 = (const float*)d_in[7];
    const float* dec_b0 = (const float*)d_in[8];
    const float* dec_w1 = (const float*)d_in[9];
    const float* dec_b1 = (const float*)d_in[10];
    const float* dec_w2 = (const float*)d_in[11];
    const float* dec_b2 = (const float*)d_in[12];
    const float* gleak  = (const float*)d_in[13];
    const float* vleak  = (const float*)d_in[14];
    const float* cm     = (const float*)d_in[15];
    const float* w      = (const float*)d_in[16];
    const float* mu     = (const float*)d_in[17];
    const float* sigma  = (const float*)d_in[18];
    const float* erev   = (const float*)d_in[19];
    const float* sw     = (const float*)d_in[20];
    const float* smu    = (const float*)d_in[21];
    const float* ssigma = (const float*)d_in[22];
    const float* serev  = (const float*)d_in[23];
    const float* in_w   = (const float*)d_in[24];
    const float* in_b   = (const float*)d_in[25];
    const float* out_w  = (const float*)d_in[26];
    const float* out_b  = (const float*)d_in[27];

    float* ws   = (float*)d_ws;
    float* buf1 = ws;                       // 16384*500
    float* buf2 = ws + 8192000;             // 16384*500
    float* hbuf = ws + 16384000;            // 16384*20
    float* mbuf = ws + 16384000 + 327680;   // 16384*4

    dim3 blk(256);
    // encoder
    gemm_bias<true ><<<dim3(8, 256), blk, 0, stream>>>(x,    enc_w0, enc_b0, buf1, 16384, 500, 39);
    gemm_bias<true ><<<dim3(8, 256), blk, 0, stream>>>(buf1, enc_w1, enc_b1, buf2, 16384, 500, 500);
    gemm_bias<false><<<dim3(1, 256), blk, 0, stream>>>(buf2, enc_w2, enc_b2, hbuf, 16384, 20, 500);
    // LTC scan
    ltc_scan<<<dim3(32), dim3(512), 0, stream>>>(hbuf, gleak, vleak, cm, w, mu, sigma, erev,
                                                 sw, smu, ssigma, serev, in_w, in_b, out_w, out_b, mbuf);
    // decoder
    dec_l1<<<dim3(8000), blk, 0, stream>>>(mbuf, dec_w0, dec_b0, buf1);
    gemm_bias<true ><<<dim3(8, 256), blk, 0, stream>>>(buf1, dec_w1, dec_b1, buf2, 16384, 500, 500);
    gemm_bias<false><<<dim3(1, 256), blk, 0, stream>>>(buf2, dec_w2, dec_b2, (float*)d_out, 16384, 30, 500);
}

// Round 8
// 2112.788 us; speedup vs baseline: 4.4036x; 1.1382x over previous
//
#include <hip/hip_runtime.h>
#include <cstdint>

// ---------------- fast device math (raw v_exp_f32 / v_rcp_f32) ----------------
__device__ __forceinline__ float fexp2(float x) { return __builtin_amdgcn_exp2f(x); }
__device__ __forceinline__ float frcp(float x)  { return __builtin_amdgcn_rcpf(x); }

__device__ __forceinline__ float fast_tanh(float x) {
    x = fminf(15.0f, fmaxf(-15.0f, x));
    float E = fexp2(x * 2.8853900817779268f);   // exp(2x) = 2^(2x*log2e)
    float d = E + 1.0f;
    float r = frcp(d);
    r = r * (2.0f - d * r);                      // Newton -> ~fp32 precise
    return (E - 1.0f) * r;
}

// ---------------- tiled fp32 GEMM: C[M][N] = act(A[M][K] @ W[K][N] + bias) ----
#define BM 64
#define BN 64
#define BK 16

template<bool TANH>
__global__ __launch_bounds__(256) void gemm_bias(
    const float* __restrict__ A, const float* __restrict__ W,
    const float* __restrict__ bias, float* __restrict__ C,
    int M, int N, int K)
{
    __shared__ float As[BK][BM + 4];
    __shared__ float Bs[BK][BN + 4];

    const int tid = threadIdx.x;
    const int tx = tid & 15;
    const int ty = tid >> 4;
    const int m0 = blockIdx.y * BM;
    const int n0 = blockIdx.x * BN;

    float acc[4][4] = {};

    for (int k0 = 0; k0 < K; k0 += BK) {
        #pragma unroll
        for (int ld = 0; ld < 4; ++ld) {
            int e  = tid + ld * 256;
            int kk = e & 15, mm = e >> 4;
            int kg = k0 + kk;
            As[kk][mm] = (kg < K) ? A[(size_t)(m0 + mm) * K + kg] : 0.0f;
        }
        #pragma unroll
        for (int ld = 0; ld < 4; ++ld) {
            int e  = tid + ld * 256;
            int nn = e & 63, kk = e >> 6;
            int kg = k0 + kk, ng = n0 + nn;
            Bs[kk][nn] = (kg < K && ng < N) ? W[(size_t)kg * N + ng] : 0.0f;
        }
        __syncthreads();

        #pragma unroll
        for (int kk = 0; kk < BK; ++kk) {
            float4 a  = *(const float4*)&As[kk][ty * 4];
            float4 bq = *(const float4*)&Bs[kk][tx * 4];
            float av[4] = {a.x, a.y, a.z, a.w};
            float bv[4] = {bq.x, bq.y, bq.z, bq.w};
            #pragma unroll
            for (int i2 = 0; i2 < 4; ++i2)
                #pragma unroll
                for (int j2 = 0; j2 < 4; ++j2)
                    acc[i2][j2] += av[i2] * bv[j2];
        }
        __syncthreads();
    }

    const int cbase = n0 + tx * 4;
    if (cbase >= N) return;

    float bb[4];
    if (cbase + 3 < N) {
        float4 b4 = *(const float4*)&bias[cbase];
        bb[0] = b4.x; bb[1] = b4.y; bb[2] = b4.z; bb[3] = b4.w;
    } else {
        #pragma unroll
        for (int e = 0; e < 4; ++e) bb[e] = (cbase + e < N) ? bias[cbase + e] : 0.0f;
    }

    #pragma unroll
    for (int i2 = 0; i2 < 4; ++i2) {
        int row = m0 + ty * 4 + i2;
        float o[4];
        #pragma unroll
        for (int j2 = 0; j2 < 4; ++j2) {
            float v = acc[i2][j2] + bb[j2];
            o[j2] = TANH ? fast_tanh(v) : v;
        }
        if (cbase + 3 < N) {
            float4 o4 = {o[0], o[1], o[2], o[3]};
            *(float4*)&C[(size_t)row * N + cbase] = o4;
        } else {
            #pragma unroll
            for (int j2 = 0; j2 < 4; ++j2)
                if (cbase + j2 < N) C[(size_t)row * N + cbase + j2] = o[j2];
        }
    }
}

// ---------------- decoder layer 1 (K=4) --------------------------------------
__global__ __launch_bounds__(256) void dec_l1(
    const float* __restrict__ Mo, const float* __restrict__ Wd,
    const float* __restrict__ bd, float* __restrict__ O)
{
    int idx = blockIdx.x * 256 + threadIdx.x;
    int r  = idx / 125;
    int c4 = (idx % 125) * 4;
    float4 m = *(const float4*)&Mo[(size_t)r * 4];
    float4 w0 = *(const float4*)&Wd[0 * 500 + c4];
    float4 w1 = *(const float4*)&Wd[1 * 500 + c4];
    float4 w2 = *(const float4*)&Wd[2 * 500 + c4];
    float4 w3 = *(const float4*)&Wd[3 * 500 + c4];
    float4 b  = *(const float4*)&bd[c4];
    float o0 = b.x + m.x * w0.x + m.y * w1.x + m.z * w2.x + m.w * w3.x;
    float o1 = b.y + m.x * w0.y + m.y * w1.y + m.z * w2.y + m.w * w3.y;
    float o2 = b.z + m.x * w0.z + m.y * w1.z + m.z * w2.z + m.w * w3.z;
    float o3 = b.w + m.x * w0.w + m.y * w1.w + m.z * w2.w + m.w * w3.w;
    float4 o = {fast_tanh(o0), fast_tanh(o1), fast_tanh(o2), fast_tanh(o3)};
    *(float4*)&O[(size_t)r * 500 + c4] = o;
}

// ---------------- LTC scan: split-j butterfly --------------------------------
// 1 block/batch, 8 waves (512 thr). Wave w owns OUTPUT slice j in [8w,8w+8).
// Lane l: jl = l&7 (j = 8w+jl), ig = l>>3 (presynaptic i in [8ig, 8ig+8)).
// Per unfold: read v[64] from LDS (2x b128, broadcast within jl-groups),
// 8 syn (fma+exp+rcp, independent chains), butterfly reduce over ig bits
// (shfl_xor 8/16/32 - intra-wave, replaces R5's post-barrier 16 LDS reads +
// 16-deep add chains), compute vj, 8 lanes/wave write v to LDS, ONE barrier.
// This shortens the barrier-to-barrier serial chain (~260 -> ~130 cyc post-
// barrier); issue count unchanged vs R5 (latency was the binding constraint:
// R2~R5 wave-doubling neutral, R7 issue-cut regressed, R6 atomics exploded).
#define SEQ_T 512

__global__ __launch_bounds__(512, 2) void ltc_scan(
    const float* __restrict__ h,       // [32][512][20]
    const float* __restrict__ gleak, const float* __restrict__ vleak,
    const float* __restrict__ cm,
    const float* __restrict__ w,  const float* __restrict__ mu,
    const float* __restrict__ sg, const float* __restrict__ erev,
    const float* __restrict__ sw,  const float* __restrict__ smu,
    const float* __restrict__ ssg, const float* __restrict__ serev,
    const float* __restrict__ in_w, const float* __restrict__ in_b,
    const float* __restrict__ out_w, const float* __restrict__ out_b,
    float* __restrict__ motor)         // [32][512][4]
{
    const int b   = blockIdx.x;
    const int tid = threadIdx.x;
    const int w8  = tid >> 6;          // wave 0..7
    const int l   = tid & 63;
    const int jl  = l & 7;
    const int ig  = l >> 3;
    const int j   = 8 * w8 + jl;       // this lane's output unit

    const float LOG2E = 1.4426950408889634f;

    __shared__ float vbuf[2][64];

    // unfold params for (i = 8*ig + r, j)
    float A1[8], B1[8], Wp[8], WE[8];
    #pragma unroll
    for (int r = 0; r < 8; ++r) {
        int i = 8 * ig + r;
        float s = sg[i * 64 + j];
        A1[r] = s * LOG2E;
        B1[r] = mu[i * 64 + j] * s * LOG2E;
        Wp[r] = w[i * 64 + j];
        WE[r] = Wp[r] * erev[i * 64 + j];
    }
    // sensory: lane handles i in {ig, ig+8, ig+16 if ig<4} for its j
    float sA[3], sB[3], sWp[3], sWE[3], uw[3], ub[3];
    int   sI[3];
    #pragma unroll
    for (int r = 0; r < 3; ++r) {
        int i = ig + 8 * r;
        bool live = (i < 20);
        sI[r] = live ? i : 0;
        float s = ssg[sI[r] * 64 + j];
        sA[r]  = s * LOG2E;
        sB[r]  = smu[sI[r] * 64 + j] * s * LOG2E;
        sWp[r] = live ? sw[sI[r] * 64 + j] : 0.0f;
        sWE[r] = live ? sWp[r] * serev[sI[r] * 64 + j] : 0.0f;
        uw[r]  = in_w[sI[r]];
        ub[r]  = in_b[sI[r]];
    }

    const float cmt  = cm[j] * 6.0f;
    const float gl   = gleak[j];
    const float glvl = gl * vleak[j];
    const float gle  = cmt + gl + 1e-8f;
    const float ow   = out_w[j & 3], ob = out_b[j & 3];

    float vj = 0.0f;                   // this lane's own v_j
    const float* hb = h + (size_t)b * SEQ_T * 20;
    float* mb = motor + (size_t)b * SEQ_T * 4;

    float u_cur[3], u_nxt[3];
    #pragma unroll
    for (int r = 0; r < 3; ++r) u_cur[r] = hb[sI[r]];

    if (tid < 64) vbuf[0][tid] = 0.0f;
    __syncthreads();

    int cur = 0;
    for (int t = 0; t < SEQ_T; ++t) {
        int tn = (t + 1 < SEQ_T) ? (t + 1) : t;
        #pragma unroll
        for (int r = 0; r < 3; ++r) u_nxt[r] = hb[tn * 20 + sI[r]];

        // sensory per-lane partial, butterfly-reduced once per t
        float ns = 0.0f, ds = 0.0f;
        #pragma unroll
        for (int r = 0; r < 3; ++r) {
            float ui = fmaf(u_cur[r], uw[r], ub[r]);
            float x  = sB[r] - ui * sA[r];
            float E  = fexp2(x);
            float s  = frcp(1.0f + E);
            ns = fmaf(sWE[r], s, ns);
            ds = fmaf(sWp[r], s, ds);
        }
        ns += __shfl_xor(ns, 8);  ds += __shfl_xor(ds, 8);
        ns += __shfl_xor(ns, 16); ds += __shfl_xor(ds, 16);
        ns += __shfl_xor(ns, 32); ds += __shfl_xor(ds, 32);
        // now ns/ds hold the full 20-synapse sensory sums for unit j

        #pragma unroll 1
        for (int uf = 0; uf < 6; ++uf) {
            float4 va = *(const float4*)&vbuf[cur][8 * ig];
            float4 vc = *(const float4*)&vbuf[cur][8 * ig + 4];
            float vv[8] = {va.x, va.y, va.z, va.w, vc.x, vc.y, vc.z, vc.w};

            float an = 0.0f, ad = 0.0f;
            #pragma unroll
            for (int r = 0; r < 8; ++r) {
                float x = fmaf(-vv[r], A1[r], B1[r]);
                float E = fexp2(x);
                float s = frcp(1.0f + E);
                an = fmaf(WE[r], s, an);
                ad = fmaf(Wp[r], s, ad);
            }
            // butterfly over ig bits (8,16,32): intra-wave, no LDS
            an += __shfl_xor(an, 8);  ad += __shfl_xor(ad, 8);
            an += __shfl_xor(an, 16); ad += __shfl_xor(ad, 16);
            an += __shfl_xor(an, 32); ad += __shfl_xor(ad, 32);

            float num = fmaf(cmt, vj, glvl) + an + ns;
            float den = gle + ad + ds;
            vj = num * frcp(den);

            if (ig == 0) vbuf[cur ^ 1][j] = vj;
            __syncthreads();
            cur ^= 1;
        }

        if (w8 == 0 && ig == 0 && jl < 4) mb[t * 4 + jl] = fmaf(vj, ow, ob);

        #pragma unroll
        for (int r = 0; r < 3; ++r) u_cur[r] = u_nxt[r];
    }
}

// ---------------- launch --------------------------------------------------
extern "C" void kernel_launch(void* const* d_in, const int* in_sizes, int n_in,
                              void* d_out, int out_size, void* d_ws, size_t ws_size,
                              hipStream_t stream) {
    const float* x      = (const float*)d_in[0];
    const float* enc_w0 = (const float*)d_in[1];
    const float* enc_b0 = (const float*)d_in[2];
    const float* enc_w1 = (const float*)d_in[3];
    const float* enc_b1 = (const float*)d_in[4];
    const float* enc_w2 = (const float*)d_in[5];
    const float* enc_b2 = (const float*)d_in[6];
    const float* dec_w0 = (const float*)d_in[7];
    const float* dec_b0 = (const float*)d_in[8];
    const float* dec_w1 = (const float*)d_in[9];
    const float* dec_b1 = (const float*)d_in[10];
    const float* dec_w2 = (const float*)d_in[11];
    const float* dec_b2 = (const float*)d_in[12];
    const float* gleak  = (const float*)d_in[13];
    const float* vleak  = (const float*)d_in[14];
    const float* cm     = (const float*)d_in[15];
    const float* w      = (const float*)d_in[16];
    const float* mu     = (const float*)d_in[17];
    const float* sigma  = (const float*)d_in[18];
    const float* erev   = (const float*)d_in[19];
    const float* sw     = (const float*)d_in[20];
    const float* smu    = (const float*)d_in[21];
    const float* ssigma = (const float*)d_in[22];
    const float* serev  = (const float*)d_in[23];
    const float* in_w   = (const float*)d_in[24];
    const float* in_b   = (const float*)d_in[25];
    const float* out_w  = (const float*)d_in[26];
    const float* out_b  = (const float*)d_in[27];

    float* ws   = (float*)d_ws;
    float* buf1 = ws;                       // 16384*500
    float* buf2 = ws + 8192000;             // 16384*500
    float* hbuf = ws + 16384000;            // 16384*20
    float* mbuf = ws + 16384000 + 327680;   // 16384*4

    dim3 blk(256);
    // encoder
    gemm_bias<true ><<<dim3(8, 256), blk, 0, stream>>>(x,    enc_w0, enc_b0, buf1, 16384, 500, 39);
    gemm_bias<true ><<<dim3(8, 256), blk, 0, stream>>>(buf1, enc_w1, enc_b1, buf2, 16384, 500, 500);
    gemm_bias<false><<<dim3(1, 256), blk, 0, stream>>>(buf2, enc_w2, enc_b2, hbuf, 16384, 20, 500);
    // LTC scan
    ltc_scan<<<dim3(32), dim3(512), 0, stream>>>(hbuf, gleak, vleak, cm, w, mu, sigma, erev,
                                                 sw, smu, ssigma, serev, in_w, in_b, out_w, out_b, mbuf);
    // decoder
    dec_l1<<<dim3(8000), blk, 0, stream>>>(mbuf, dec_w0, dec_b0, buf1);
    gemm_bias<true ><<<dim3(8, 256), blk, 0, stream>>>(buf1, dec_w1, dec_b1, buf2, 16384, 500, 500);
    gemm_bias<false><<<dim3(1, 256), blk, 0, stream>>>(buf2, dec_w2, dec_b2, (float*)d_out, 16384, 30, 500);
}